// Round 1
// baseline (22810.516 us; speedup 1.0000x reference)
//
#include <hip/hip_runtime.h>
#include <math.h>

#define B_    32
#define S_    512
#define EMB_  512
#define HID_  1024
#define LAB_  64
#define M_    (B_ * S_)

// ---------------------------------------------------------------------------
// R10 exchange: flag-gated, single-shot data loads.
//   data : u64 = packed float2 {h[b0], h[b1]} per neuron.
//          layout [2 slots][16 groups][1024 neurons]            (256 KB)
//   flags: u64 (low32 = tag) per producer WAVE (8 neurons).
//          layout [2 slots][16 groups][128 = neuron>>3]          ( 32 KB)
// Producer wave: 8 float2 stores (even lanes) -> RELEASE flag store (lane 0).
// Consumer thread: polls its 2 flags (8 lanes share each address ->
// coalesced; s_sleep backoff), then loads its 2 data words ONCE.
// Replaces the R9 scheme where 512 threads re-polled 2048 tagged words per
// step per WG (~25 iterations/step, rocprof VALU evidence) and saturated
// the XCD L2 atomic pipes.
// Slot-reuse safety (depth 2, unchanged induction): storing flag t implies
// this WG consumed all of t-1, which implies every group member published
// t-1, which (program order + data dependency) implies every member
// finished reading slot t-2 before it gets overwritten at t.
// Tags: layer0 1..512, layer1 513..1024; logits/0/0xAA never match.
// ---------------------------------------------------------------------------
#define EX2_WORDS  (16 * 1024)        // u64 per data slot
#define FLAG_BASE  (2 * EX2_WORDS)    // u64 offset of flag region
#define FLAG_WORDS (16 * 128)         // u64 per flag slot

__device__ __forceinline__ unsigned long long aload64(const unsigned long long* p) {
    return __hip_atomic_load((unsigned long long*)p, __ATOMIC_RELAXED,
                             __HIP_MEMORY_SCOPE_AGENT);
}
__device__ __forceinline__ void astore64(unsigned long long* p, unsigned long long v) {
    __hip_atomic_store(p, v, __ATOMIC_RELAXED, __HIP_MEMORY_SCOPE_AGENT);
}
__device__ __forceinline__ void astore64_rel(unsigned long long* p, unsigned long long v) {
    __hip_atomic_store(p, v, __ATOMIC_RELEASE, __HIP_MEMORY_SCOPE_AGENT);
}

// ---------------------------------------------------------------------------
// fp32 tiled GEMM, BM=128, BN=64, BK=16, 256 threads, 8x4/thread (measured
// ~0.79 ms total across the three projections). Optional row-gather on A.
// ---------------------------------------------------------------------------
__global__ __launch_bounds__(256) void gemm_bias(
    const float* __restrict__ A, const int* __restrict__ tokens,
    const float* __restrict__ W, const float* __restrict__ bias,
    const float* __restrict__ bias2, float* __restrict__ C,
    int M, int K, int N)
{
    __shared__ float As[128][17];
    __shared__ float Ws[64][17];

    const int tid = threadIdx.x;
    const int tx  = tid & 15;
    const int ty  = tid >> 4;
    const int n0  = blockIdx.x * 64;
    const int m0  = blockIdx.y * 128;

    const int lr  = tid >> 2;
    const int lk  = (tid & 3) << 2;

    const int ar0 = tokens ? tokens[m0 + lr]      : (m0 + lr);
    const int ar1 = tokens ? tokens[m0 + 64 + lr] : (m0 + 64 + lr);
    const float* __restrict__ arow0 = A + (size_t)ar0 * K;
    const float* __restrict__ arow1 = A + (size_t)ar1 * K;
    const float* __restrict__ wrow  = W + (size_t)(n0 + lr) * K;

    float bs[4];
#pragma unroll
    for (int j = 0; j < 4; ++j) {
        int n = n0 + tx * 4 + j;
        bs[j] = bias[n] + (bias2 ? bias2[n] : 0.0f);
    }

    float acc[8][4] = {};

    for (int k0 = 0; k0 < K; k0 += 16) {
        const float4 a0 = *(const float4*)(arow0 + k0 + lk);
        const float4 a1 = *(const float4*)(arow1 + k0 + lk);
        const float4 wv = *(const float4*)(wrow  + k0 + lk);
        __syncthreads();
        As[lr][lk + 0] = a0.x; As[lr][lk + 1] = a0.y;
        As[lr][lk + 2] = a0.z; As[lr][lk + 3] = a0.w;
        As[64 + lr][lk + 0] = a1.x; As[64 + lr][lk + 1] = a1.y;
        As[64 + lr][lk + 2] = a1.z; As[64 + lr][lk + 3] = a1.w;
        Ws[lr][lk + 0] = wv.x; Ws[lr][lk + 1] = wv.y;
        Ws[lr][lk + 2] = wv.z; Ws[lr][lk + 3] = wv.w;
        __syncthreads();

#pragma unroll
        for (int kk = 0; kk < 16; ++kk) {
            float b[4], a[8];
#pragma unroll
            for (int j = 0; j < 4; ++j) b[j] = Ws[tx * 4 + j][kk];
#pragma unroll
            for (int i = 0; i < 8; ++i) a[i] = As[ty * 8 + i][kk];
#pragma unroll
            for (int i = 0; i < 8; ++i)
#pragma unroll
                for (int j = 0; j < 4; ++j)
                    acc[i][j] += a[i] * b[j];
        }
    }

#pragma unroll
    for (int i = 0; i < 8; ++i) {
        const int m = m0 + ty * 8 + i;
        float4 v;
        v.x = acc[i][0] + bs[0];
        v.y = acc[i][1] + bs[1];
        v.z = acc[i][2] + bs[2];
        v.w = acc[i][3] + bs[3];
        *(float4*)(C + (size_t)m * N + n0 + tx * 4) = v;
    }
}

// ---------------------------------------------------------------------------
// Weight-stationary persistent scan, R10: flag-gated exchange.
// 256 WGs x 512 threads, 1 WG/CU. Group = wg&15 (16 groups x 2 batches,
// XCD-affine perf heuristic only). Slice s = wg>>4: 64 neurons.
// Weights in registers: 8 neurons x 16 strided k = 128 VGPRs.
// LDS h: float2[2][1024] double-buffered -> ONE barrier per step (at the
// start of compute). Safety: a thread's reads of buf[(t-1)&1] precede
// (program order) its staging of buf[t&1], which precedes barrier_t; any
// thread writes buf[(t+1)&1] = buf[(t-1)&1] only after passing barrier_t.
// 16-acc halving-tree reduction: after masks 1,2,4,8 + 16,32, lane p
// holds out(p&15).
// ---------------------------------------------------------------------------
__global__ __launch_bounds__(512, 2) void rnn_scan_tag(
    const float* __restrict__ Whh,          // [H][H] row-major
    float* __restrict__ x,                  // [B,S,H]  xp in, h out (in place)
    unsigned long long* __restrict__ ex,    // data + flag exchange (d_out)
    unsigned tag0)                          // 1 (layer0) / 513 (layer1)
{
    extern __shared__ float smem[];
    float2* hb2 = (float2*)smem;            // [2][1024] float2 = 16 KB

    const int wg  = blockIdx.x;
    const int bg  = wg & 15;         // batch group (2 batches)
    const int s   = wg >> 4;         // slice 0..15 (64 neurons)
    const int tid = threadIdx.x;     // 0..511
    const int j8  = tid >> 6;        // wave 0..7 -> neurons s*64 + j8*8 ..+7
    const int kg  = tid & 63;        // lane; k = kg + 64q
    const int b0  = bg * 2;

    // weights: 8 neurons x 16 strided k = 128 VGPRs (lane-coalesced loads)
    float wreg[8][16];
    {
        const float* wb = Whh + (size_t)(s * 64 + j8 * 8) * HID_ + kg;
#pragma unroll
        for (int i = 0; i < 8; ++i)
#pragma unroll
            for (int q = 0; q < 16; ++q)
                wreg[i][q] = wb[(size_t)i * HID_ + q * 64];
    }

    const int oi = (kg >> 1) & 7, ob = kg & 1;     // lane's output (kg<16)
    const int ok = s * 64 + j8 * 8 + oi;           // neuron index

    // group-local exchange pointers, both slots
    unsigned long long* const exd0 = ex + (size_t)bg * 1024;
    unsigned long long* const exd1 = exd0 + EX2_WORDS;
    unsigned long long* const exf0 = ex + FLAG_BASE + (size_t)bg * 128;
    unsigned long long* const exf1 = exf0 + FLAG_WORDS;

    // consumer word indices: data neurons tid, tid+512; their wave-flags
    const int dn0 = tid, dn1 = tid + 512;
    const int fn0 = tid >> 3, fn1 = 64 + (tid >> 3);   // = neuron>>3

    // producer word indices
    const int pubn = ok;              // data (even lanes, kg<16)
    const int pubf = s * 8 + j8;      // wave flag (lane kg==0)

    // incremental xp/h pointer (kg<16 lanes only)
    float* px = x + (size_t)(b0 + ob) * S_ * HID_ + ok;

    for (int t = 0; t < S_; ++t) {
        float2* cur = hb2 + (size_t)(t & 1) * HID_;

        // ---- xp prefetch: independent of h, overlaps the flag poll ----
        float xpv = 0.f;
        if (kg < 16) xpv = *px;

        // ---- stage h_{t-1}: flag-gated, single-shot data loads ----
        if (t > 0) {
            const unsigned wtag = tag0 + (unsigned)(t - 1);
            unsigned long long* const exd = ((t - 1) & 1) ? exd1 : exd0;
            unsigned long long* const exf = ((t - 1) & 1) ? exf1 : exf0;

            unsigned pend = 3u;
            do {
                if (pend & 1u)
                    if ((unsigned)aload64(exf + fn0) == wtag) pend &= ~1u;
                if (pend & 2u)
                    if ((unsigned)aload64(exf + fn1) == wtag) pend &= ~2u;
                if (pend) __builtin_amdgcn_s_sleep(1);   // spin backoff
            } while (pend);

            const unsigned long long d0 = aload64(exd + dn0);
            const unsigned long long d1 = aload64(exd + dn1);
            float2 v0, v1;
            v0.x = __uint_as_float((unsigned)d0);
            v0.y = __uint_as_float((unsigned)(d0 >> 32));
            v1.x = __uint_as_float((unsigned)d1);
            v1.y = __uint_as_float((unsigned)(d1 >> 32));
            cur[dn0] = v0;                 // contiguous b64: conflict-free
            cur[dn1] = v1;
        } else {
            cur[dn0] = make_float2(0.f, 0.f);
            cur[dn1] = make_float2(0.f, 0.f);
        }
        __syncthreads();   // the ONE barrier: staging done -> compute reads

        // ---- partials: v[a], a = i*2+b, over 16 strided k ----
        float v[16] = {};
#pragma unroll
        for (int q = 0; q < 16; ++q) {
            const float2 hv = cur[kg + 64 * q];    // lane-contig b64: free
#pragma unroll
            for (int i = 0; i < 8; ++i) {
                const float w = wreg[i][q];
                v[i * 2 + 0] += w * hv.x;
                v[i * 2 + 1] += w * hv.y;
            }
        }

        // ---- halving-tree reduction: 15+2 shfls fold 16 accs -> 1 ----
#pragma unroll
        for (int st = 0; st < 4; ++st) {
            const int m  = 1 << st;
            const int nh = 8 >> st;
            const bool hi = (kg & m) != 0;
#pragma unroll
            for (int j = 0; j < 8; ++j) {
                if (j < nh) {
                    const float a0 = v[2 * j], a1 = v[2 * j + 1];
                    const float got = __shfl_xor(hi ? a0 : a1, m, 64);
                    v[j] = (hi ? a1 : a0) + got;
                }
            }
        }
        v[0] += __shfl_xor(v[0], 16, 64);
        v[0] += __shfl_xor(v[0], 32, 64);
        // lane p now holds out(p & 15), a = i*2+b

        // ---- publish: pair-packed data stores, then RELEASE wave flag ----
        float hv = 0.f;
        if (kg < 16) {
            hv = tanhf(xpv + v[0]);
            *px = hv;                   // for the next-layer GEMM
            px += HID_;
        }
        const float hvp = __shfl_xor(hv, 1, 64);   // partner batch, same neuron
        {
            unsigned long long* const exd = (t & 1) ? exd1 : exd0;
            if (kg < 16 && (kg & 1) == 0) {
                // even lane: ob=0 -> low word = batch b0, high = batch b1
                const unsigned long long u =
                    ((unsigned long long)__float_as_uint(hvp) << 32) |
                    (unsigned long long)__float_as_uint(hv);
                astore64(exd + pubn, u);
            }
        }
        if (kg == 0) {
            unsigned long long* const exf = (t & 1) ? exf1 : exf0;
            // RELEASE: drains this wave's data stores before the flag lands
            astore64_rel(exf + pubf,
                         (unsigned long long)(tag0 + (unsigned)t));
        }
        // no trailing barrier: double-buffered hb2 (see header comment)
    }
}

__global__ __launch_bounds__(256) void copy4(
    const float4* __restrict__ src, float4* __restrict__ dst, int n4)
{
    const int i = blockIdx.x * 256 + threadIdx.x;
    if (i < n4) dst[i] = src[i];
}

extern "C" void kernel_launch(void* const* d_in, const int* in_sizes, int n_in,
                              void* d_out, int out_size, void* d_ws, size_t ws_size,
                              hipStream_t stream)
{
    const int*   tokens = (const int*)  d_in[0];
    const float* emb    = (const float*)d_in[1];
    const float* W_ih0  = (const float*)d_in[2];
    const float* W_hh0  = (const float*)d_in[3];
    const float* b_ih0  = (const float*)d_in[4];
    const float* b_hh0  = (const float*)d_in[5];
    const float* W_ih1  = (const float*)d_in[6];
    const float* W_hh1  = (const float*)d_in[7];
    const float* b_ih1  = (const float*)d_in[8];
    const float* b_hh1  = (const float*)d_in[9];
    const float* W_out  = (const float*)d_in[10];
    const float* b_out  = (const float*)d_in[11];
    float* out = (float*)d_out;

    const size_t BUF = (size_t)B_ * S_ * HID_;   // 64 MiB
    float* buf  = (float*)d_ws;
    float* buf1 = buf + BUF;                     // only if ws_size permits
    float* tmp  = (float*)d_out;                 // chunk bounce (fallback)
    unsigned long long* ex = (unsigned long long*)d_out;  // 288 KB exchange

    const int two_buf = (ws_size >= 2 * BUF * sizeof(float));  // constant/call

    // 96 KB dynamic LDS -> exactly 1 WG/CU (256 WGs co-resident on 256 CUs)
    const size_t scan_lds = 98304;
    hipFuncSetAttribute((const void*)rnn_scan_tag,
                        hipFuncAttributeMaxDynamicSharedMemorySize, (int)scan_lds);

    // 1) xp0 = gather(emb,tokens) @ W_ih0^T + b_ih0 + b_hh0  -> buf
    gemm_bias<<<dim3(HID_ / 64, M_ / 128), 256, 0, stream>>>(
        emb, tokens, W_ih0, b_ih0, b_hh0, buf, M_, EMB_, HID_);

    // 2) layer-0 scan (in place on buf; tags 1..512)
    rnn_scan_tag<<<256, 512, scan_lds, stream>>>(W_hh0, buf, ex, 1u);

    float* l1buf;
    if (two_buf) {
        // 3a) full-grid xp1 GEMM into buf1
        gemm_bias<<<dim3(HID_ / 64, M_ / 128), 256, 0, stream>>>(
            buf, nullptr, W_ih1, b_ih1, b_hh1, buf1, M_, HID_, HID_);
        l1buf = buf1;
    } else {
        // 3b) fallback: chunk through d_out (ex region dead until next scan)
        for (int c = 0; c < 16; ++c) {
            const float* Ac = buf + (size_t)c * 1024 * HID_;
            gemm_bias<<<dim3(HID_ / 64, 1024 / 128), 256, 0, stream>>>(
                Ac, nullptr, W_ih1, b_ih1, b_hh1, tmp, 1024, HID_, HID_);
            copy4<<<1024, 256, 0, stream>>>(
                (const float4*)tmp, (float4*)(buf + (size_t)c * 1024 * HID_),
                1024 * HID_ / 4);
        }
        l1buf = buf;
    }

    // 4) layer-1 scan (tags 513..1024; stale/garbage high words never match)
    rnn_scan_tag<<<256, 512, scan_lds, stream>>>(W_hh1, l1buf, ex, 513u);

    // 5) out = h1 @ W_out^T + b_out (fully rewrites d_out incl. ex region)
    gemm_bias<<<dim3(LAB_ / 64, M_ / 128), 256, 0, stream>>>(
        l1buf, nullptr, W_out, b_out, nullptr, out, M_, HID_, LAB_);
}

// Round 2
// 6141.763 us; speedup vs baseline: 3.7140x; 3.7140x over previous
//
#include <hip/hip_runtime.h>
#include <math.h>

#define B_    32
#define S_    512
#define EMB_  512
#define HID_  1024
#define LAB_  64
#define M_    (B_ * S_)

// ---------------------------------------------------------------------------
// R11 exchange: flag-gated, single-shot data loads, MANUAL release.
//   data : u64 = packed float2 {h[b0], h[b1]} per neuron.
//          layout [2 slots][16 groups][1024 neurons]            (256 KB)
//   flags: u64 (low32 = tag) per producer WAVE (8 neurons).
//          layout [2 slots][16 groups][128 = neuron>>3]          ( 32 KB)
// Producer wave: 8 float2 stores (even lanes) -> s_waitcnt vmcnt(0) ->
// relaxed flag store (lane 0). The data stores are sc0/sc1 write-through
// atomics (bypass L2, ack at the coherence point), so vmcnt(0) IS a full
// release for this protocol. Do NOT use __ATOMIC_RELEASE: on gfx950 agent
// scope it emits buffer_wbl2 (full L2 writeback per wave per step) -- the
// R10 post-mortem showed that costs ~45k cycles/step (10.9 ms scans,
// VALUBusy 5.6%).
// Consumer thread: spins (no s_sleep -- quantization hurts the 512-step
// serial chain) on its 2 flag words (8 lanes share each address -> 16x
// fewer poll requests than R9's data-word polling), then asm-fenced
// single-shot data loads (fence stops compiler hoisting the relaxed loads
// above the flag check; no buffer_inv).
// Slot-reuse safety (depth 2, unchanged induction): storing flag t implies
// this WG consumed all of t-1 (post-barrier), which implies every group
// member published t-1, which implies every member finished reading slot
// t-2 before it is overwritten at t.
// Tags: layer0 1..512, layer1 513..1024; logits/0/0xAA never match.
// ---------------------------------------------------------------------------
#define EX2_WORDS  (16 * 1024)        // u64 per data slot
#define FLAG_BASE  (2 * EX2_WORDS)    // u64 offset of flag region
#define FLAG_WORDS (16 * 128)         // u64 per flag slot

__device__ __forceinline__ unsigned long long aload64(const unsigned long long* p) {
    return __hip_atomic_load((unsigned long long*)p, __ATOMIC_RELAXED,
                             __HIP_MEMORY_SCOPE_AGENT);
}
__device__ __forceinline__ void astore64(unsigned long long* p, unsigned long long v) {
    __hip_atomic_store(p, v, __ATOMIC_RELAXED, __HIP_MEMORY_SCOPE_AGENT);
}
// Wave-wide wait for all outstanding vector-memory ops (incl. every lane's
// sc0/sc1 stores' coherence-point acks). "memory" clobber pins compiler order.
__device__ __forceinline__ void vm_drain() {
    asm volatile("s_waitcnt vmcnt(0)" ::: "memory");
}

// ---------------------------------------------------------------------------
// fp32 tiled GEMM, BM=128, BN=64, BK=16, 256 threads, 8x4/thread (measured
// ~0.79 ms total across the three projections). Optional row-gather on A.
// ---------------------------------------------------------------------------
__global__ __launch_bounds__(256) void gemm_bias(
    const float* __restrict__ A, const int* __restrict__ tokens,
    const float* __restrict__ W, const float* __restrict__ bias,
    const float* __restrict__ bias2, float* __restrict__ C,
    int M, int K, int N)
{
    __shared__ float As[128][17];
    __shared__ float Ws[64][17];

    const int tid = threadIdx.x;
    const int tx  = tid & 15;
    const int ty  = tid >> 4;
    const int n0  = blockIdx.x * 64;
    const int m0  = blockIdx.y * 128;

    const int lr  = tid >> 2;
    const int lk  = (tid & 3) << 2;

    const int ar0 = tokens ? tokens[m0 + lr]      : (m0 + lr);
    const int ar1 = tokens ? tokens[m0 + 64 + lr] : (m0 + 64 + lr);
    const float* __restrict__ arow0 = A + (size_t)ar0 * K;
    const float* __restrict__ arow1 = A + (size_t)ar1 * K;
    const float* __restrict__ wrow  = W + (size_t)(n0 + lr) * K;

    float bs[4];
#pragma unroll
    for (int j = 0; j < 4; ++j) {
        int n = n0 + tx * 4 + j;
        bs[j] = bias[n] + (bias2 ? bias2[n] : 0.0f);
    }

    float acc[8][4] = {};

    for (int k0 = 0; k0 < K; k0 += 16) {
        const float4 a0 = *(const float4*)(arow0 + k0 + lk);
        const float4 a1 = *(const float4*)(arow1 + k0 + lk);
        const float4 wv = *(const float4*)(wrow  + k0 + lk);
        __syncthreads();
        As[lr][lk + 0] = a0.x; As[lr][lk + 1] = a0.y;
        As[lr][lk + 2] = a0.z; As[lr][lk + 3] = a0.w;
        As[64 + lr][lk + 0] = a1.x; As[64 + lr][lk + 1] = a1.y;
        As[64 + lr][lk + 2] = a1.z; As[64 + lr][lk + 3] = a1.w;
        Ws[lr][lk + 0] = wv.x; Ws[lr][lk + 1] = wv.y;
        Ws[lr][lk + 2] = wv.z; Ws[lr][lk + 3] = wv.w;
        __syncthreads();

#pragma unroll
        for (int kk = 0; kk < 16; ++kk) {
            float b[4], a[8];
#pragma unroll
            for (int j = 0; j < 4; ++j) b[j] = Ws[tx * 4 + j][kk];
#pragma unroll
            for (int i = 0; i < 8; ++i) a[i] = As[ty * 8 + i][kk];
#pragma unroll
            for (int i = 0; i < 8; ++i)
#pragma unroll
                for (int j = 0; j < 4; ++j)
                    acc[i][j] += a[i] * b[j];
        }
    }

#pragma unroll
    for (int i = 0; i < 8; ++i) {
        const int m = m0 + ty * 8 + i;
        float4 v;
        v.x = acc[i][0] + bs[0];
        v.y = acc[i][1] + bs[1];
        v.z = acc[i][2] + bs[2];
        v.w = acc[i][3] + bs[3];
        *(float4*)(C + (size_t)m * N + n0 + tx * 4) = v;
    }
}

// ---------------------------------------------------------------------------
// Weight-stationary persistent scan, R11: flag-gated exchange, manual fence.
// 256 WGs x 512 threads, 1 WG/CU. Group = wg&15 (16 groups x 2 batches,
// XCD-affine perf heuristic only). Slice s = wg>>4: 64 neurons.
// Weights in registers: 8 neurons x 16 strided k = 128 VGPRs.
// LDS h: float2[2][1024] double-buffered -> ONE barrier per step. Safety: a
// thread's reads of buf[(t-1)&1] precede (program order) its staging of
// buf[t&1], which precedes barrier_t; any thread writes buf[(t+1)&1] =
// buf[(t-1)&1] only after passing barrier_t. 16-acc halving-tree
// reduction: after masks 1,2,4,8 + 16,32, lane p holds out(p&15).
// ---------------------------------------------------------------------------
__global__ __launch_bounds__(512, 2) void rnn_scan_tag(
    const float* __restrict__ Whh,          // [H][H] row-major
    float* __restrict__ x,                  // [B,S,H]  xp in, h out (in place)
    unsigned long long* __restrict__ ex,    // data + flag exchange (d_out)
    unsigned tag0)                          // 1 (layer0) / 513 (layer1)
{
    extern __shared__ float smem[];
    float2* hb2 = (float2*)smem;            // [2][1024] float2 = 16 KB

    const int wg  = blockIdx.x;
    const int bg  = wg & 15;         // batch group (2 batches)
    const int s   = wg >> 4;         // slice 0..15 (64 neurons)
    const int tid = threadIdx.x;     // 0..511
    const int j8  = tid >> 6;        // wave 0..7 -> neurons s*64 + j8*8 ..+7
    const int kg  = tid & 63;        // lane; k = kg + 64q
    const int b0  = bg * 2;

    // weights: 8 neurons x 16 strided k = 128 VGPRs (lane-coalesced loads)
    float wreg[8][16];
    {
        const float* wb = Whh + (size_t)(s * 64 + j8 * 8) * HID_ + kg;
#pragma unroll
        for (int i = 0; i < 8; ++i)
#pragma unroll
            for (int q = 0; q < 16; ++q)
                wreg[i][q] = wb[(size_t)i * HID_ + q * 64];
    }

    const int oi = (kg >> 1) & 7, ob = kg & 1;     // lane's output (kg<16)
    const int ok = s * 64 + j8 * 8 + oi;           // neuron index

    // group-local exchange pointers, both slots
    unsigned long long* const exd0 = ex + (size_t)bg * 1024;
    unsigned long long* const exd1 = exd0 + EX2_WORDS;
    unsigned long long* const exf0 = ex + FLAG_BASE + (size_t)bg * 128;
    unsigned long long* const exf1 = exf0 + FLAG_WORDS;

    // consumer word indices: data neurons tid, tid+512; their wave-flags
    const int dn0 = tid, dn1 = tid + 512;
    const int fn0 = tid >> 3, fn1 = 64 + (tid >> 3);   // = neuron>>3

    // producer word indices
    const int pubn = ok;              // data (even lanes, kg<16)
    const int pubf = s * 8 + j8;      // wave flag (lane kg==0)

    // incremental xp/h pointer (kg<16 lanes only)
    float* px = x + (size_t)(b0 + ob) * S_ * HID_ + ok;

    for (int t = 0; t < S_; ++t) {
        float2* cur = hb2 + (size_t)(t & 1) * HID_;

        // ---- xp prefetch: independent of h, overlaps the flag poll ----
        float xpv = 0.f;
        if (kg < 16) xpv = *px;

        // ---- stage h_{t-1}: flag-gated, single-shot data loads ----
        if (t > 0) {
            const unsigned wtag = tag0 + (unsigned)(t - 1);
            unsigned long long* const exd = ((t - 1) & 1) ? exd1 : exd0;
            unsigned long long* const exf = ((t - 1) & 1) ? exf1 : exf0;

            unsigned pend = 3u;
            do {
                if (pend & 1u)
                    if ((unsigned)aload64(exf + fn0) == wtag) pend &= ~1u;
                if (pend & 2u)
                    if ((unsigned)aload64(exf + fn1) == wtag) pend &= ~2u;
            } while (pend);

            // fence: data loads must not be hoisted above the flag match
            vm_drain();

            const unsigned long long d0 = aload64(exd + dn0);
            const unsigned long long d1 = aload64(exd + dn1);
            float2 v0, v1;
            v0.x = __uint_as_float((unsigned)d0);
            v0.y = __uint_as_float((unsigned)(d0 >> 32));
            v1.x = __uint_as_float((unsigned)d1);
            v1.y = __uint_as_float((unsigned)(d1 >> 32));
            cur[dn0] = v0;                 // contiguous b64: conflict-free
            cur[dn1] = v1;
        } else {
            cur[dn0] = make_float2(0.f, 0.f);
            cur[dn1] = make_float2(0.f, 0.f);
        }
        __syncthreads();   // the ONE barrier: staging done -> compute reads

        // ---- partials: v[a], a = i*2+b, over 16 strided k ----
        float v[16] = {};
#pragma unroll
        for (int q = 0; q < 16; ++q) {
            const float2 hv = cur[kg + 64 * q];    // lane-contig b64: free
#pragma unroll
            for (int i = 0; i < 8; ++i) {
                const float w = wreg[i][q];
                v[i * 2 + 0] += w * hv.x;
                v[i * 2 + 1] += w * hv.y;
            }
        }

        // ---- halving-tree reduction: 15+2 shfls fold 16 accs -> 1 ----
#pragma unroll
        for (int st = 0; st < 4; ++st) {
            const int m  = 1 << st;
            const int nh = 8 >> st;
            const bool hi = (kg & m) != 0;
#pragma unroll
            for (int j = 0; j < 8; ++j) {
                if (j < nh) {
                    const float a0 = v[2 * j], a1 = v[2 * j + 1];
                    const float got = __shfl_xor(hi ? a0 : a1, m, 64);
                    v[j] = (hi ? a1 : a0) + got;
                }
            }
        }
        v[0] += __shfl_xor(v[0], 16, 64);
        v[0] += __shfl_xor(v[0], 32, 64);
        // lane p now holds out(p & 15), a = i*2+b

        // ---- publish: pair-packed data stores, vmcnt drain, wave flag ----
        float hv = 0.f;
        if (kg < 16) {
            hv = tanhf(xpv + v[0]);
            *px = hv;                   // for the next-layer GEMM
            px += HID_;
        }
        const float hvp = __shfl_xor(hv, 1, 64);   // partner batch, same neuron
        {
            unsigned long long* const exd = (t & 1) ? exd1 : exd0;
            if (kg < 16 && (kg & 1) == 0) {
                // even lane: ob=0 -> low word = batch b0, high = batch b1
                const unsigned long long u =
                    ((unsigned long long)__float_as_uint(hvp) << 32) |
                    (unsigned long long)__float_as_uint(hv);
                astore64(exd + pubn, u);
            }
        }
        // manual release: wait for this wave's data stores to reach the
        // coherence point, then publish the flag (relaxed, no wbl2)
        vm_drain();
        if (kg == 0) {
            unsigned long long* const exf = (t & 1) ? exf1 : exf0;
            astore64(exf + pubf,
                     (unsigned long long)(tag0 + (unsigned)t));
        }
        // no trailing barrier: double-buffered hb2 (see header comment)
    }
}

__global__ __launch_bounds__(256) void copy4(
    const float4* __restrict__ src, float4* __restrict__ dst, int n4)
{
    const int i = blockIdx.x * 256 + threadIdx.x;
    if (i < n4) dst[i] = src[i];
}

extern "C" void kernel_launch(void* const* d_in, const int* in_sizes, int n_in,
                              void* d_out, int out_size, void* d_ws, size_t ws_size,
                              hipStream_t stream)
{
    const int*   tokens = (const int*)  d_in[0];
    const float* emb    = (const float*)d_in[1];
    const float* W_ih0  = (const float*)d_in[2];
    const float* W_hh0  = (const float*)d_in[3];
    const float* b_ih0  = (const float*)d_in[4];
    const float* b_hh0  = (const float*)d_in[5];
    const float* W_ih1  = (const float*)d_in[6];
    const float* W_hh1  = (const float*)d_in[7];
    const float* b_ih1  = (const float*)d_in[8];
    const float* b_hh1  = (const float*)d_in[9];
    const float* W_out  = (const float*)d_in[10];
    const float* b_out  = (const float*)d_in[11];
    float* out = (float*)d_out;

    const size_t BUF = (size_t)B_ * S_ * HID_;   // 64 MiB
    float* buf  = (float*)d_ws;
    float* buf1 = buf + BUF;                     // only if ws_size permits
    float* tmp  = (float*)d_out;                 // chunk bounce (fallback)
    unsigned long long* ex = (unsigned long long*)d_out;  // 288 KB exchange

    const int two_buf = (ws_size >= 2 * BUF * sizeof(float));  // constant/call

    // 96 KB dynamic LDS -> exactly 1 WG/CU (256 WGs co-resident on 256 CUs)
    const size_t scan_lds = 98304;
    hipFuncSetAttribute((const void*)rnn_scan_tag,
                        hipFuncAttributeMaxDynamicSharedMemorySize, (int)scan_lds);

    // 1) xp0 = gather(emb,tokens) @ W_ih0^T + b_ih0 + b_hh0  -> buf
    gemm_bias<<<dim3(HID_ / 64, M_ / 128), 256, 0, stream>>>(
        emb, tokens, W_ih0, b_ih0, b_hh0, buf, M_, EMB_, HID_);

    // 2) layer-0 scan (in place on buf; tags 1..512)
    rnn_scan_tag<<<256, 512, scan_lds, stream>>>(W_hh0, buf, ex, 1u);

    float* l1buf;
    if (two_buf) {
        // 3a) full-grid xp1 GEMM into buf1
        gemm_bias<<<dim3(HID_ / 64, M_ / 128), 256, 0, stream>>>(
            buf, nullptr, W_ih1, b_ih1, b_hh1, buf1, M_, HID_, HID_);
        l1buf = buf1;
    } else {
        // 3b) fallback: chunk through d_out (ex region dead until next scan)
        for (int c = 0; c < 16; ++c) {
            const float* Ac = buf + (size_t)c * 1024 * HID_;
            gemm_bias<<<dim3(HID_ / 64, 1024 / 128), 256, 0, stream>>>(
                Ac, nullptr, W_ih1, b_ih1, b_hh1, tmp, 1024, HID_, HID_);
            copy4<<<1024, 256, 0, stream>>>(
                (const float4*)tmp, (float4*)(buf + (size_t)c * 1024 * HID_),
                1024 * HID_ / 4);
        }
        l1buf = buf;
    }

    // 4) layer-1 scan (tags 513..1024; stale/garbage high words never match)
    rnn_scan_tag<<<256, 512, scan_lds, stream>>>(W_hh1, l1buf, ex, 513u);

    // 5) out = h1 @ W_out^T + b_out (fully rewrites d_out incl. ex region)
    gemm_bias<<<dim3(LAB_ / 64, M_ / 128), 256, 0, stream>>>(
        l1buf, nullptr, W_out, b_out, nullptr, out, M_, HID_, LAB_);
}